// Round 8
// baseline (210.485 us; speedup 1.0000x reference)
//
#include <hip/hip_runtime.h>
#include <math.h>

#define FFT_N 16384
#define NT 512
#define RPT 32
#define B_DIM 8
#define H_DIM 256

// Per-wave LDS region: 2048 elements + 1/16 pad (hand-verified <=2-way banks
// for every access map below; 2-way is free per m136).
#define REGION 2048
#define RW (REGION + (REGION >> 4))      // 2176 floats per region per plane
#define I16(x) ((x) + ((x) >> 4))

// Intra-wave LDS fence: DS ops from one wave complete in order; this stops the
// compiler from reordering the read loop before the write loop and drains the
// pipe as insurance.
#define WAVE_LDS_FENCE() do {                                   \
    __builtin_amdgcn_sched_barrier(0);                          \
    asm volatile("s_waitcnt lgkmcnt(0)" ::: "memory");          \
    __builtin_amdgcn_sched_barrier(0);                          \
} while (0)

__device__ __forceinline__ float2 cmul(float2 a, float2 b) {
    return make_float2(a.x * b.x - a.y * b.y, a.x * b.y + a.y * b.x);
}
__device__ __forceinline__ float2 cadd(float2 a, float2 b) { return make_float2(a.x + b.x, a.y + b.y); }
__device__ __forceinline__ float2 csub(float2 a, float2 b) { return make_float2(a.x - b.x, a.y - b.y); }
__device__ __forceinline__ float2 mulnegi(float2 z) { return make_float2(z.y, -z.x); }   // -i*z
__device__ __forceinline__ float2 mulposi(float2 z) { return make_float2(-z.y, z.x); }   // +i*z

// ---- radix-4 butterflies (verified R1..R7) ----
__device__ __forceinline__ void bfly4(float2& a, float2& b, float2& c, float2& d,
                                      float2 w1, float2 w2, float2 w3) {
    float2 apc = cadd(a, c), amc = csub(a, c);
    float2 bpd = cadd(b, d), bmd = csub(b, d);
    float2 nib = mulnegi(bmd);
    a = cadd(apc, bpd);
    b = cmul(csub(apc, bpd), w2);
    c = cmul(cadd(amc, nib), w1);
    d = cmul(csub(amc, nib), w3);
}
__device__ __forceinline__ void bfly4_nw(float2& a, float2& b, float2& c, float2& d) {
    float2 apc = cadd(a, c), amc = csub(a, c);
    float2 bpd = cadd(b, d), bmd = csub(b, d);
    float2 nib = mulnegi(bmd);
    a = cadd(apc, bpd);
    b = csub(apc, bpd);
    c = cadd(amc, nib);
    d = csub(amc, nib);
}
__device__ __forceinline__ void ibfly4(float2& a, float2& b, float2& c, float2& d,
                                       float2 w1t, float2 w2t) {
    float2 w1 = make_float2(w1t.x, -w1t.y);
    float2 w2 = make_float2(w2t.x, -w2t.y);
    float2 bt = cmul(b, w2), dt = cmul(d, w2);
    float2 A = cadd(a, bt), Bb = csub(a, bt);
    float2 C = cadd(c, dt), Dd = csub(c, dt);
    float2 Cw = cmul(C, w1);
    float2 Dw = mulposi(cmul(Dd, w1));
    a = cadd(A, Cw);  c = csub(A, Cw);
    b = cadd(Bb, Dw); d = csub(Bb, Dw);
}
__device__ __forceinline__ void ibfly4_nw(float2& a, float2& b, float2& c, float2& d) {
    float2 A = cadd(a, b), Bb = csub(a, b);
    float2 C = cadd(c, d), Dd = csub(c, d);
    float2 Dw = mulposi(Dd);
    a = cadd(A, C);  c = csub(A, C);
    b = cadd(Bb, Dw); d = csub(Bb, Dw);
}

// ---- global stages 0,1 on nA regs (verified R5..R7) ----
__device__ __forceinline__ void fwd_g01(float2 r[RPT], int lp, const float2* __restrict__ tw) {
#pragma unroll
    for (int j0 = 0; j0 < 8; ++j0) {
        const int i = lp + NT * j0;
        bfly4(r[j0], r[j0 + 8], r[j0 + 16], r[j0 + 24], tw[i], tw[2 * i], tw[3 * i]);
    }
    {
        const int ie = lp * 4, io = (lp + NT) * 4;
        const float2 we1 = tw[ie], we2 = tw[2 * ie], we3 = tw[3 * ie];
        const float2 wo1 = tw[io], wo2 = tw[2 * io], wo3 = tw[3 * io];
#pragma unroll
        for (int m = 0; m < 8; ++m) {
            const int g = (m >> 1) * 8 + (m & 1);
            if (g & 1) bfly4(r[g], r[g + 2], r[g + 4], r[g + 6], wo1, wo2, wo3);
            else       bfly4(r[g], r[g + 2], r[g + 4], r[g + 6], we1, we2, we3);
        }
    }
}
__device__ __forceinline__ void inv_g01(float2 r[RPT], int lp, const float2* __restrict__ tw) {
    {
        const int ie = lp * 4, io = (lp + NT) * 4;
        const float2 we1 = tw[ie], we2 = tw[2 * ie];
        const float2 wo1 = tw[io], wo2 = tw[2 * io];
#pragma unroll
        for (int m = 0; m < 8; ++m) {
            const int g = (m >> 1) * 8 + (m & 1);
            if (g & 1) ibfly4(r[g], r[g + 2], r[g + 4], r[g + 6], wo1, wo2);
            else       ibfly4(r[g], r[g + 2], r[g + 4], r[g + 6], we1, we2);
        }
    }
#pragma unroll
    for (int j0 = 0; j0 < 8; ++j0) {
        const int i = lp + NT * j0;
        ibfly4(r[j0], r[j0 + 8], r[j0 + 16], r[j0 + 24], tw[i], tw[2 * i]);
    }
}

// Layouts (element e = 2048*w + eloc):
//  nA: r[j]        <-> e    = t + 512*j
//  W1: r[16s+jj]   <-> eloc = 1024*s + 64*jj + l          (stages q=256,64)
//  W2: r[16s+jj]   <-> eloc = 1024*s + 64*(l>>2) + 4*jj + (l&3)   (q=16,4)
//  W3: r[16s+jj]   <-> eloc = 1024*s + 16*l + jj          (q=1)

// forward middle: entry exchange + 5 wave-local stages, ends in W3 regs
__device__ __forceinline__ void fwd_mid(float2 r[RPT], float* ldsx, float* ldsy,
                                        const int t, const int w, const int l,
                                        const float2* __restrict__ tw) {
    // entry exchange: write nA (cross-region), ONE barrier, read W1 (region-private)
#pragma unroll
    for (int j = 0; j < RPT; ++j) {
        const int e = t + NT * j;
        const int a = (e >> 11) * RW + I16(e & 2047);
        ldsx[a] = r[j].x; ldsy[a] = r[j].y;
    }
    __syncthreads();
#pragma unroll
    for (int s = 0; s < 2; ++s)
#pragma unroll
        for (int jj = 0; jj < 16; ++jj) {
            const int a = w * RW + I16(1024 * s + 64 * jj + l);
            r[16 * s + jj].x = ldsx[a];
            r[16 * s + jj].y = ldsy[a];
        }
    // W1 phase: stage q=256 (twiddle i1 = (e1 mod 256)*16)
#pragma unroll
    for (int j0 = 0; j0 < 4; ++j0) {
        const int i1 = 1024 * j0 + 16 * l;
        const float2 w1 = tw[i1], w2 = tw[2 * i1], w3 = tw[3 * i1];
#pragma unroll
        for (int s = 0; s < 2; ++s)
            bfly4(r[16 * s + j0], r[16 * s + j0 + 4], r[16 * s + j0 + 8], r[16 * s + j0 + 12], w1, w2, w3);
    }
    // stage q=64 (twiddle i2 = 64*l, lane-uniform over jj)
    {
        const int i2 = 64 * l;
        const float2 w1 = tw[i2], w2 = tw[2 * i2], w3 = tw[3 * i2];
#pragma unroll
        for (int s = 0; s < 2; ++s)
#pragma unroll
            for (int g = 0; g < 4; ++g)
                bfly4(r[16 * s + 4 * g], r[16 * s + 4 * g + 1], r[16 * s + 4 * g + 2], r[16 * s + 4 * g + 3], w1, w2, w3);
    }
    // wave-local exchange W1 -> W2 (no workgroup barrier)
#pragma unroll
    for (int s = 0; s < 2; ++s)
#pragma unroll
        for (int jj = 0; jj < 16; ++jj) {
            const int a = w * RW + I16(1024 * s + 64 * jj + l);
            ldsx[a] = r[16 * s + jj].x; ldsy[a] = r[16 * s + jj].y;
        }
    WAVE_LDS_FENCE();
    {
        const int lo = 64 * (l >> 2) + (l & 3);
#pragma unroll
        for (int s = 0; s < 2; ++s)
#pragma unroll
            for (int jj = 0; jj < 16; ++jj) {
                const int a = w * RW + I16(1024 * s + lo + 4 * jj);
                r[16 * s + jj].x = ldsx[a]; r[16 * s + jj].y = ldsy[a];
            }
    }
    // W2 phase: stage q=16 (i3 = (e1 mod 16)*256)
#pragma unroll
    for (int j0 = 0; j0 < 4; ++j0) {
        const int i3 = 1024 * j0 + 256 * (l & 3);
        const float2 w1 = tw[i3], w2 = tw[2 * i3], w3 = tw[3 * i3];
#pragma unroll
        for (int s = 0; s < 2; ++s)
            bfly4(r[16 * s + j0], r[16 * s + j0 + 4], r[16 * s + j0 + 8], r[16 * s + j0 + 12], w1, w2, w3);
    }
    // stage q=4 (i4 = 1024*(l&3), lane-uniform over jj)
    {
        const int i4 = 1024 * (l & 3);
        const float2 w1 = tw[i4], w2 = tw[2 * i4], w3 = tw[3 * i4];
#pragma unroll
        for (int s = 0; s < 2; ++s)
#pragma unroll
            for (int g = 0; g < 4; ++g)
                bfly4(r[16 * s + 4 * g], r[16 * s + 4 * g + 1], r[16 * s + 4 * g + 2], r[16 * s + 4 * g + 3], w1, w2, w3);
    }
    // wave-local exchange W2 -> W3
    {
        const int lo = 64 * (l >> 2) + (l & 3);
#pragma unroll
        for (int s = 0; s < 2; ++s)
#pragma unroll
            for (int jj = 0; jj < 16; ++jj) {
                const int a = w * RW + I16(1024 * s + lo + 4 * jj);
                ldsx[a] = r[16 * s + jj].x; ldsy[a] = r[16 * s + jj].y;
            }
    }
    WAVE_LDS_FENCE();
#pragma unroll
    for (int s = 0; s < 2; ++s)
#pragma unroll
        for (int jj = 0; jj < 16; ++jj) {
            const int a = w * RW + I16(1024 * s + 16 * l + jj);
            r[16 * s + jj].x = ldsx[a]; r[16 * s + jj].y = ldsy[a];
        }
    // W3 phase: stage q=1 (twiddle-free)
#pragma unroll
    for (int s = 0; s < 2; ++s)
#pragma unroll
        for (int g = 0; g < 4; ++g)
            bfly4_nw(r[16 * s + 4 * g], r[16 * s + 4 * g + 1], r[16 * s + 4 * g + 2], r[16 * s + 4 * g + 3]);
}

// inverse middle: starts in W3 regs, ends in nA regs (5 wave-local stages + exit exchange)
__device__ __forceinline__ void inv_mid(float2 r[RPT], float* ldsx, float* ldsy,
                                        const int t, const int w, const int l,
                                        const float2* __restrict__ tw) {
    // inv stage q=1
#pragma unroll
    for (int s = 0; s < 2; ++s)
#pragma unroll
        for (int g = 0; g < 4; ++g)
            ibfly4_nw(r[16 * s + 4 * g], r[16 * s + 4 * g + 1], r[16 * s + 4 * g + 2], r[16 * s + 4 * g + 3]);
    // wave-local exchange W3 -> W2
#pragma unroll
    for (int s = 0; s < 2; ++s)
#pragma unroll
        for (int jj = 0; jj < 16; ++jj) {
            const int a = w * RW + I16(1024 * s + 16 * l + jj);
            ldsx[a] = r[16 * s + jj].x; ldsy[a] = r[16 * s + jj].y;
        }
    WAVE_LDS_FENCE();
    {
        const int lo = 64 * (l >> 2) + (l & 3);
#pragma unroll
        for (int s = 0; s < 2; ++s)
#pragma unroll
            for (int jj = 0; jj < 16; ++jj) {
                const int a = w * RW + I16(1024 * s + lo + 4 * jj);
                r[16 * s + jj].x = ldsx[a]; r[16 * s + jj].y = ldsy[a];
            }
    }
    // inv stage q=4 (uniform), then q=16
    {
        const int i4 = 1024 * (l & 3);
        const float2 w1 = tw[i4], w2 = tw[2 * i4];
#pragma unroll
        for (int s = 0; s < 2; ++s)
#pragma unroll
            for (int g = 0; g < 4; ++g)
                ibfly4(r[16 * s + 4 * g], r[16 * s + 4 * g + 1], r[16 * s + 4 * g + 2], r[16 * s + 4 * g + 3], w1, w2);
    }
#pragma unroll
    for (int j0 = 0; j0 < 4; ++j0) {
        const int i3 = 1024 * j0 + 256 * (l & 3);
        const float2 w1 = tw[i3], w2 = tw[2 * i3];
#pragma unroll
        for (int s = 0; s < 2; ++s)
            ibfly4(r[16 * s + j0], r[16 * s + j0 + 4], r[16 * s + j0 + 8], r[16 * s + j0 + 12], w1, w2);
    }
    // wave-local exchange W2 -> W1
    {
        const int lo = 64 * (l >> 2) + (l & 3);
#pragma unroll
        for (int s = 0; s < 2; ++s)
#pragma unroll
            for (int jj = 0; jj < 16; ++jj) {
                const int a = w * RW + I16(1024 * s + lo + 4 * jj);
                ldsx[a] = r[16 * s + jj].x; ldsy[a] = r[16 * s + jj].y;
            }
    }
    WAVE_LDS_FENCE();
#pragma unroll
    for (int s = 0; s < 2; ++s)
#pragma unroll
        for (int jj = 0; jj < 16; ++jj) {
            const int a = w * RW + I16(1024 * s + 64 * jj + l);
            r[16 * s + jj].x = ldsx[a]; r[16 * s + jj].y = ldsy[a];
        }
    // inv stage q=64 (uniform), then q=256
    {
        const int i2 = 64 * l;
        const float2 w1 = tw[i2], w2 = tw[2 * i2];
#pragma unroll
        for (int s = 0; s < 2; ++s)
#pragma unroll
            for (int g = 0; g < 4; ++g)
                ibfly4(r[16 * s + 4 * g], r[16 * s + 4 * g + 1], r[16 * s + 4 * g + 2], r[16 * s + 4 * g + 3], w1, w2);
    }
#pragma unroll
    for (int j0 = 0; j0 < 4; ++j0) {
        const int i1 = 1024 * j0 + 16 * l;
        const float2 w1 = tw[i1], w2 = tw[2 * i1];
#pragma unroll
        for (int s = 0; s < 2; ++s)
            ibfly4(r[16 * s + j0], r[16 * s + j0 + 4], r[16 * s + j0 + 8], r[16 * s + j0 + 12], w1, w2);
    }
    // exit exchange: write W1 (region-private), ONE barrier, read nA (cross-region)
#pragma unroll
    for (int s = 0; s < 2; ++s)
#pragma unroll
        for (int jj = 0; jj < 16; ++jj) {
            const int a = w * RW + I16(1024 * s + 64 * jj + l);
            ldsx[a] = r[16 * s + jj].x; ldsy[a] = r[16 * s + jj].y;
        }
    __syncthreads();
#pragma unroll
    for (int j = 0; j < RPT; ++j) {
        const int e = t + NT * j;
        const int a = (e >> 11) * RW + I16(e & 2047);
        r[j].x = ldsx[a]; r[j].y = ldsy[a];
    }
}

__device__ __forceinline__ float ftanh(float x) {
    float e = __expf(2.0f * x);
    return 1.0f - 2.0f * __builtin_amdgcn_rcpf(e + 1.0f);
}

__global__ void twiddle_init(float2* __restrict__ tw) {
    int t = blockIdx.x * blockDim.x + threadIdx.x;
    if (t < FFT_N) {
        float ang = -2.0f * 3.14159265358979323846f * (float)t / (float)FFT_N;
        float sv, cv;
        sincosf(ang, &sv, &cv);
        tw[t] = make_float2(cv, sv);
    }
}

// Forward FFT of (k_h + dh*delta) -> Kf[h], stored in thread-linear W3 order.
// __launch_bounds__(512,2): 2 waves/EU min -> VGPR cap 256 -> no scratch spill.
__global__ __launch_bounds__(NT, 2) void kfft_kernel(const float* __restrict__ k,
                                                     const float* __restrict__ D,
                                                     const float2* __restrict__ tw,
                                                     float2* __restrict__ Kf) {
    __shared__ float ldsx[8 * RW];
    __shared__ float ldsy[8 * RW];
    const int h = blockIdx.x;
    const int t = threadIdx.x;
    const int w = t >> 6, l = t & 63;
    const float* krow = k + (size_t)h * FFT_N;
    float2 r[RPT];
#pragma unroll
    for (int j = 0; j < RPT; ++j) r[j] = make_float2(krow[t + NT * j], 0.f);
    if (t == 0) r[0].x += D[h * (H_DIM + 1)];
    fwd_g01(r, t, tw);
    fwd_mid(r, ldsx, ldsy, t, w, l, tw);
    float4* out4 = (float4*)(Kf + (size_t)h * FFT_N);
#pragma unroll
    for (int m = 0; m < 16; ++m)
        out4[16 * t + m] = make_float4(r[2 * m].x, r[2 * m].y, r[2 * m + 1].x, r[2 * m + 1].y);
}

// Batch rows (2p,h) and (2p+1,h) packed as z = u0 + i*u1.
__global__ __launch_bounds__(NT, 2) void conv_kernel(const float* __restrict__ u,
                                                     const float2* __restrict__ tw,
                                                     const float2* __restrict__ Kf,
                                                     float* __restrict__ out) {
    __shared__ float ldsx[8 * RW];
    __shared__ float ldsy[8 * RW];
    // XCD-chunked bijection (1024 blocks, 1024%8==0): blocks sharing h colocate per XCD
    const int raw = blockIdx.x;
    const int vb = ((raw & 7) << 7) + (raw >> 3);
    const int h = vb >> 2;
    const int p = vb & 3;
    const int t = threadIdx.x;
    const int w = t >> 6, l = t & 63;
    const size_t row0 = ((size_t)(2 * p) * H_DIM + h) * FFT_N;
    const size_t row1 = row0 + (size_t)H_DIM * FFT_N;
    const float* u0 = u + row0;
    const float* u1 = u + row1;

    float2 r[RPT];
#pragma unroll
    for (int j = 0; j < RPT; ++j) {
        const int n = t + NT * j;
        r[j] = make_float2(u0[n], u1[n]);
    }

    fwd_g01(r, t, tw);
    fwd_mid(r, ldsx, ldsy, t, w, l, tw);

    // pointwise multiply in thread-linear W3 order (matches kfft) + 1/N
    {
        const float4* kf4 = (const float4*)(Kf + (size_t)h * FFT_N);
        const float invN = 1.0f / (float)FFT_N;
#pragma unroll
        for (int m = 0; m < 16; ++m) {
            const float4 q = kf4[16 * t + m];
            const float2 z0 = r[2 * m], z1 = r[2 * m + 1];
            r[2 * m]     = make_float2((z0.x * q.x - z0.y * q.y) * invN,
                                       (z0.x * q.y + z0.y * q.x) * invN);
            r[2 * m + 1] = make_float2((z1.x * q.z - z1.y * q.w) * invN,
                                       (z1.x * q.w + z1.y * q.z) * invN);
        }
    }

    inv_mid(r, ldsx, ldsy, t, w, l, tw);
    inv_g01(r, t, tw);

    float* o0 = out + row0;
    float* o1 = out + row1;
#pragma unroll
    for (int j = 0; j < RPT; ++j) {
        const int n = t + NT * j;
        o0[n] = ftanh(r[j].x);
        o1[n] = ftanh(r[j].y);
    }
}

extern "C" void kernel_launch(void* const* d_in, const int* in_sizes, int n_in,
                              void* d_out, int out_size, void* d_ws, size_t ws_size,
                              hipStream_t stream) {
    const float* u = (const float*)d_in[0];   // (B,H,L) f32
    const float* k = (const float*)d_in[1];   // (H,L)   f32
    const float* D = (const float*)d_in[2];   // (H,H)   f32
    float* out = (float*)d_out;

    float2* tw = (float2*)d_ws;               // 16384 float2 = 128 KiB
    float2* Kf = tw + FFT_N;                  // 256*16384 float2 = 32 MiB

    twiddle_init<<<FFT_N / 256, 256, 0, stream>>>(tw);
    kfft_kernel<<<H_DIM, NT, 0, stream>>>(k, D, tw, Kf);
    conv_kernel<<<(B_DIM / 2) * H_DIM, NT, 0, stream>>>(u, tw, Kf, out);
}

// Round 9
// 199.318 us; speedup vs baseline: 1.0560x; 1.0560x over previous
//
#include <hip/hip_runtime.h>
#include <math.h>

#define FFT_N 16384
#define NT 512
#define RPT 32
#define B_DIM 8
#define H_DIM 256

// Per-wave LDS region, pad 1 float per 32 (R2-proven scheme): every access
// map below lands <=2 lanes/bank (2-way is free, m136).
#define REGION 2048
#define RW (REGION + (REGION >> 5))      // 2112 floats per region per plane; 2112%32==0
#define PAD(x) ((x) + ((x) >> 5))

// Intra-wave LDS fence (verified R7): DS ops of one wave complete in order;
// fence stops compiler reordering and drains the LDS pipe.
#define WAVE_LDS_FENCE() do {                                   \
    __builtin_amdgcn_sched_barrier(0);                          \
    asm volatile("s_waitcnt lgkmcnt(0)" ::: "memory");          \
    __builtin_amdgcn_sched_barrier(0);                          \
} while (0)

__device__ __forceinline__ float2 cmul(float2 a, float2 b) {
    return make_float2(a.x * b.x - a.y * b.y, a.x * b.y + a.y * b.x);
}
__device__ __forceinline__ float2 cadd(float2 a, float2 b) { return make_float2(a.x + b.x, a.y + b.y); }
__device__ __forceinline__ float2 csub(float2 a, float2 b) { return make_float2(a.x - b.x, a.y - b.y); }
__device__ __forceinline__ float2 mulnegi(float2 z) { return make_float2(z.y, -z.x); }   // -i*z
__device__ __forceinline__ float2 mulposi(float2 z) { return make_float2(-z.y, z.x); }   // +i*z

// ---- radix-4 butterflies (verified R1..R8) ----
__device__ __forceinline__ void bfly4(float2& a, float2& b, float2& c, float2& d,
                                      float2 w1, float2 w2, float2 w3) {
    float2 apc = cadd(a, c), amc = csub(a, c);
    float2 bpd = cadd(b, d), bmd = csub(b, d);
    float2 nib = mulnegi(bmd);
    a = cadd(apc, bpd);
    b = cmul(csub(apc, bpd), w2);
    c = cmul(cadd(amc, nib), w1);
    d = cmul(csub(amc, nib), w3);
}
__device__ __forceinline__ void bfly4_nw(float2& a, float2& b, float2& c, float2& d) {
    float2 apc = cadd(a, c), amc = csub(a, c);
    float2 bpd = cadd(b, d), bmd = csub(b, d);
    float2 nib = mulnegi(bmd);
    a = cadd(apc, bpd);
    b = csub(apc, bpd);
    c = cadd(amc, nib);
    d = csub(amc, nib);
}
__device__ __forceinline__ void ibfly4(float2& a, float2& b, float2& c, float2& d,
                                       float2 w1t, float2 w2t) {
    float2 w1 = make_float2(w1t.x, -w1t.y);
    float2 w2 = make_float2(w2t.x, -w2t.y);
    float2 bt = cmul(b, w2), dt = cmul(d, w2);
    float2 A = cadd(a, bt), Bb = csub(a, bt);
    float2 C = cadd(c, dt), Dd = csub(c, dt);
    float2 Cw = cmul(C, w1);
    float2 Dw = mulposi(cmul(Dd, w1));
    a = cadd(A, Cw);  c = csub(A, Cw);
    b = cadd(Bb, Dw); d = csub(Bb, Dw);
}
__device__ __forceinline__ void ibfly4_nw(float2& a, float2& b, float2& c, float2& d) {
    float2 A = cadd(a, b), Bb = csub(a, b);
    float2 C = cadd(c, d), Dd = csub(c, d);
    float2 Dw = mulposi(Dd);
    a = cadd(A, C);  c = csub(A, C);
    b = cadd(Bb, Dw); d = csub(Bb, Dw);
}

// ---- global stages 0,1 on nA regs (verified R5..R8) ----
__device__ __forceinline__ void fwd_g01(float2 r[RPT], int lp, const float2* __restrict__ tw) {
#pragma unroll
    for (int j0 = 0; j0 < 8; ++j0) {
        const int i = lp + NT * j0;
        bfly4(r[j0], r[j0 + 8], r[j0 + 16], r[j0 + 24], tw[i], tw[2 * i], tw[3 * i]);
    }
    {
        const int ie = lp * 4, io = (lp + NT) * 4;
        const float2 we1 = tw[ie], we2 = tw[2 * ie], we3 = tw[3 * ie];
        const float2 wo1 = tw[io], wo2 = tw[2 * io], wo3 = tw[3 * io];
#pragma unroll
        for (int m = 0; m < 8; ++m) {
            const int g = (m >> 1) * 8 + (m & 1);
            if (g & 1) bfly4(r[g], r[g + 2], r[g + 4], r[g + 6], wo1, wo2, wo3);
            else       bfly4(r[g], r[g + 2], r[g + 4], r[g + 6], we1, we2, we3);
        }
    }
}
__device__ __forceinline__ void inv_g01(float2 r[RPT], int lp, const float2* __restrict__ tw) {
    {
        const int ie = lp * 4, io = (lp + NT) * 4;
        const float2 we1 = tw[ie], we2 = tw[2 * ie];
        const float2 wo1 = tw[io], wo2 = tw[2 * io];
#pragma unroll
        for (int m = 0; m < 8; ++m) {
            const int g = (m >> 1) * 8 + (m & 1);
            if (g & 1) ibfly4(r[g], r[g + 2], r[g + 4], r[g + 6], wo1, wo2);
            else       ibfly4(r[g], r[g + 2], r[g + 4], r[g + 6], we1, we2);
        }
    }
#pragma unroll
    for (int j0 = 0; j0 < 8; ++j0) {
        const int i = lp + NT * j0;
        ibfly4(r[j0], r[j0 + 8], r[j0 + 16], r[j0 + 24], tw[i], tw[2 * i]);
    }
}

// Layouts (element e = 2048*w + eloc):
//  nA: r[j]        <-> e    = t + 512*j
//  W1: r[16s+jj]   <-> eloc = 1024*s + 64*jj + l          (stages q=256,64)
//  W2: r[16s+jj]   <-> eloc = 1024*s + 64*(l>>2) + 4*jj + (l&3)   (q=16,4)
//  W3: r[16s+jj]   <-> eloc = 1024*s + 16*l + jj          (q=1)

// forward middle: entry exchange + 5 wave-local stages, ends in W3 regs
__device__ __forceinline__ void fwd_mid(float2 r[RPT], float* ldsx, float* ldsy,
                                        const int t, const int w, const int l,
                                        const float2* __restrict__ tw) {
    // entry exchange: write nA (cross-region), ONE barrier, read W1 (region-private)
#pragma unroll
    for (int j = 0; j < RPT; ++j) {
        const int e = t + NT * j;
        const int a = (e >> 11) * RW + PAD(e & 2047);
        ldsx[a] = r[j].x; ldsy[a] = r[j].y;
    }
    __syncthreads();
#pragma unroll
    for (int s = 0; s < 2; ++s)
#pragma unroll
        for (int jj = 0; jj < 16; ++jj) {
            const int a = w * RW + PAD(1024 * s + 64 * jj + l);
            r[16 * s + jj].x = ldsx[a];
            r[16 * s + jj].y = ldsy[a];
        }
    // W1 phase: stage q=256 (twiddle i1 = (e1 mod 256)*16)
#pragma unroll
    for (int j0 = 0; j0 < 4; ++j0) {
        const int i1 = 1024 * j0 + 16 * l;
        const float2 w1 = tw[i1], w2 = tw[2 * i1], w3 = tw[3 * i1];
#pragma unroll
        for (int s = 0; s < 2; ++s)
            bfly4(r[16 * s + j0], r[16 * s + j0 + 4], r[16 * s + j0 + 8], r[16 * s + j0 + 12], w1, w2, w3);
    }
    // stage q=64 (twiddle i2 = 64*l, lane-uniform over jj)
    {
        const int i2 = 64 * l;
        const float2 w1 = tw[i2], w2 = tw[2 * i2], w3 = tw[3 * i2];
#pragma unroll
        for (int s = 0; s < 2; ++s)
#pragma unroll
            for (int g = 0; g < 4; ++g)
                bfly4(r[16 * s + 4 * g], r[16 * s + 4 * g + 1], r[16 * s + 4 * g + 2], r[16 * s + 4 * g + 3], w1, w2, w3);
    }
    // wave-local exchange W1 -> W2 (no workgroup barrier)
#pragma unroll
    for (int s = 0; s < 2; ++s)
#pragma unroll
        for (int jj = 0; jj < 16; ++jj) {
            const int a = w * RW + PAD(1024 * s + 64 * jj + l);
            ldsx[a] = r[16 * s + jj].x; ldsy[a] = r[16 * s + jj].y;
        }
    WAVE_LDS_FENCE();
    {
        const int lo = 64 * (l >> 2) + (l & 3);
#pragma unroll
        for (int s = 0; s < 2; ++s)
#pragma unroll
            for (int jj = 0; jj < 16; ++jj) {
                const int a = w * RW + PAD(1024 * s + lo + 4 * jj);
                r[16 * s + jj].x = ldsx[a]; r[16 * s + jj].y = ldsy[a];
            }
    }
    // W2 phase: stage q=16 (i3 = (e1 mod 16)*256)
#pragma unroll
    for (int j0 = 0; j0 < 4; ++j0) {
        const int i3 = 1024 * j0 + 256 * (l & 3);
        const float2 w1 = tw[i3], w2 = tw[2 * i3], w3 = tw[3 * i3];
#pragma unroll
        for (int s = 0; s < 2; ++s)
            bfly4(r[16 * s + j0], r[16 * s + j0 + 4], r[16 * s + j0 + 8], r[16 * s + j0 + 12], w1, w2, w3);
    }
    // stage q=4 (i4 = 1024*(l&3), lane-uniform over jj)
    {
        const int i4 = 1024 * (l & 3);
        const float2 w1 = tw[i4], w2 = tw[2 * i4], w3 = tw[3 * i4];
#pragma unroll
        for (int s = 0; s < 2; ++s)
#pragma unroll
            for (int g = 0; g < 4; ++g)
                bfly4(r[16 * s + 4 * g], r[16 * s + 4 * g + 1], r[16 * s + 4 * g + 2], r[16 * s + 4 * g + 3], w1, w2, w3);
    }
    // wave-local exchange W2 -> W3
    {
        const int lo = 64 * (l >> 2) + (l & 3);
#pragma unroll
        for (int s = 0; s < 2; ++s)
#pragma unroll
            for (int jj = 0; jj < 16; ++jj) {
                const int a = w * RW + PAD(1024 * s + lo + 4 * jj);
                ldsx[a] = r[16 * s + jj].x; ldsy[a] = r[16 * s + jj].y;
            }
    }
    WAVE_LDS_FENCE();
#pragma unroll
    for (int s = 0; s < 2; ++s)
#pragma unroll
        for (int jj = 0; jj < 16; ++jj) {
            const int a = w * RW + PAD(1024 * s + 16 * l + jj);
            r[16 * s + jj].x = ldsx[a]; r[16 * s + jj].y = ldsy[a];
        }
    // W3 phase: stage q=1 (twiddle-free)
#pragma unroll
    for (int s = 0; s < 2; ++s)
#pragma unroll
        for (int g = 0; g < 4; ++g)
            bfly4_nw(r[16 * s + 4 * g], r[16 * s + 4 * g + 1], r[16 * s + 4 * g + 2], r[16 * s + 4 * g + 3]);
}

// inverse middle: starts in W3 regs, ends in nA regs (5 wave-local stages + exit exchange)
__device__ __forceinline__ void inv_mid(float2 r[RPT], float* ldsx, float* ldsy,
                                        const int t, const int w, const int l,
                                        const float2* __restrict__ tw) {
    // inv stage q=1
#pragma unroll
    for (int s = 0; s < 2; ++s)
#pragma unroll
        for (int g = 0; g < 4; ++g)
            ibfly4_nw(r[16 * s + 4 * g], r[16 * s + 4 * g + 1], r[16 * s + 4 * g + 2], r[16 * s + 4 * g + 3]);
    // wave-local exchange W3 -> W2
#pragma unroll
    for (int s = 0; s < 2; ++s)
#pragma unroll
        for (int jj = 0; jj < 16; ++jj) {
            const int a = w * RW + PAD(1024 * s + 16 * l + jj);
            ldsx[a] = r[16 * s + jj].x; ldsy[a] = r[16 * s + jj].y;
        }
    WAVE_LDS_FENCE();
    {
        const int lo = 64 * (l >> 2) + (l & 3);
#pragma unroll
        for (int s = 0; s < 2; ++s)
#pragma unroll
            for (int jj = 0; jj < 16; ++jj) {
                const int a = w * RW + PAD(1024 * s + lo + 4 * jj);
                r[16 * s + jj].x = ldsx[a]; r[16 * s + jj].y = ldsy[a];
            }
    }
    // inv stage q=4 (uniform), then q=16
    {
        const int i4 = 1024 * (l & 3);
        const float2 w1 = tw[i4], w2 = tw[2 * i4];
#pragma unroll
        for (int s = 0; s < 2; ++s)
#pragma unroll
            for (int g = 0; g < 4; ++g)
                ibfly4(r[16 * s + 4 * g], r[16 * s + 4 * g + 1], r[16 * s + 4 * g + 2], r[16 * s + 4 * g + 3], w1, w2);
    }
#pragma unroll
    for (int j0 = 0; j0 < 4; ++j0) {
        const int i3 = 1024 * j0 + 256 * (l & 3);
        const float2 w1 = tw[i3], w2 = tw[2 * i3];
#pragma unroll
        for (int s = 0; s < 2; ++s)
            ibfly4(r[16 * s + j0], r[16 * s + j0 + 4], r[16 * s + j0 + 8], r[16 * s + j0 + 12], w1, w2);
    }
    // wave-local exchange W2 -> W1
    {
        const int lo = 64 * (l >> 2) + (l & 3);
#pragma unroll
        for (int s = 0; s < 2; ++s)
#pragma unroll
            for (int jj = 0; jj < 16; ++jj) {
                const int a = w * RW + PAD(1024 * s + lo + 4 * jj);
                ldsx[a] = r[16 * s + jj].x; ldsy[a] = r[16 * s + jj].y;
            }
    }
    WAVE_LDS_FENCE();
#pragma unroll
    for (int s = 0; s < 2; ++s)
#pragma unroll
        for (int jj = 0; jj < 16; ++jj) {
            const int a = w * RW + PAD(1024 * s + 64 * jj + l);
            r[16 * s + jj].x = ldsx[a]; r[16 * s + jj].y = ldsy[a];
        }
    // inv stage q=64 (uniform), then q=256
    {
        const int i2 = 64 * l;
        const float2 w1 = tw[i2], w2 = tw[2 * i2];
#pragma unroll
        for (int s = 0; s < 2; ++s)
#pragma unroll
            for (int g = 0; g < 4; ++g)
                ibfly4(r[16 * s + 4 * g], r[16 * s + 4 * g + 1], r[16 * s + 4 * g + 2], r[16 * s + 4 * g + 3], w1, w2);
    }
#pragma unroll
    for (int j0 = 0; j0 < 4; ++j0) {
        const int i1 = 1024 * j0 + 16 * l;
        const float2 w1 = tw[i1], w2 = tw[2 * i1];
#pragma unroll
        for (int s = 0; s < 2; ++s)
            ibfly4(r[16 * s + j0], r[16 * s + j0 + 4], r[16 * s + j0 + 8], r[16 * s + j0 + 12], w1, w2);
    }
    // exit exchange: write W1 (region-private), ONE barrier, read nA (cross-region)
#pragma unroll
    for (int s = 0; s < 2; ++s)
#pragma unroll
        for (int jj = 0; jj < 16; ++jj) {
            const int a = w * RW + PAD(1024 * s + 64 * jj + l);
            ldsx[a] = r[16 * s + jj].x; ldsy[a] = r[16 * s + jj].y;
        }
    __syncthreads();
#pragma unroll
    for (int j = 0; j < RPT; ++j) {
        const int e = t + NT * j;
        const int a = (e >> 11) * RW + PAD(e & 2047);
        r[j].x = ldsx[a]; r[j].y = ldsy[a];
    }
}

__device__ __forceinline__ float ftanh(float x) {
    float e = __expf(2.0f * x);
    return 1.0f - 2.0f * __builtin_amdgcn_rcpf(e + 1.0f);
}

__global__ void twiddle_init(float2* __restrict__ tw) {
    int t = blockIdx.x * blockDim.x + threadIdx.x;
    if (t < FFT_N) {
        float ang = -2.0f * 3.14159265358979323846f * (float)t / (float)FFT_N;
        float sv, cv;
        sincosf(ang, &sv, &cv);
        tw[t] = make_float2(cv, sv);
    }
}

// Forward FFT of (k_h + dh*delta) -> Kf[h], thread-linear W3 order.
// amdgpu_waves_per_eu(2,2): LDS already caps us at 1 block = 2 waves/EU, so
// telling the allocator max-occupancy==2 frees it to use up to 256 VGPRs
// instead of spilling to scratch at the 128 tier.
__global__ __launch_bounds__(NT)
__attribute__((amdgpu_waves_per_eu(2, 2)))
void kfft_kernel(const float* __restrict__ k,
                 const float* __restrict__ D,
                 const float2* __restrict__ tw,
                 float2* __restrict__ Kf) {
    __shared__ float ldsx[8 * RW];
    __shared__ float ldsy[8 * RW];
    const int h = blockIdx.x;
    const int t = threadIdx.x;
    const int w = t >> 6, l = t & 63;
    const float* krow = k + (size_t)h * FFT_N;
    float2 r[RPT];
#pragma unroll
    for (int j = 0; j < RPT; ++j) r[j] = make_float2(krow[t + NT * j], 0.f);
    if (t == 0) r[0].x += D[h * (H_DIM + 1)];
    fwd_g01(r, t, tw);
    fwd_mid(r, ldsx, ldsy, t, w, l, tw);
    float4* out4 = (float4*)(Kf + (size_t)h * FFT_N);
#pragma unroll
    for (int m = 0; m < 16; ++m)
        out4[16 * t + m] = make_float4(r[2 * m].x, r[2 * m].y, r[2 * m + 1].x, r[2 * m + 1].y);
}

// Batch rows (2p,h) and (2p+1,h) packed as z = u0 + i*u1.
__global__ __launch_bounds__(NT)
__attribute__((amdgpu_waves_per_eu(2, 2)))
void conv_kernel(const float* __restrict__ u,
                 const float2* __restrict__ tw,
                 const float2* __restrict__ Kf,
                 float* __restrict__ out) {
    __shared__ float ldsx[8 * RW];
    __shared__ float ldsy[8 * RW];
    // XCD-chunked bijection (1024 blocks, 1024%8==0): blocks sharing h colocate per XCD
    const int raw = blockIdx.x;
    const int vb = ((raw & 7) << 7) + (raw >> 3);
    const int h = vb >> 2;
    const int p = vb & 3;
    const int t = threadIdx.x;
    const int w = t >> 6, l = t & 63;
    const size_t row0 = ((size_t)(2 * p) * H_DIM + h) * FFT_N;
    const size_t row1 = row0 + (size_t)H_DIM * FFT_N;
    const float* u0 = u + row0;
    const float* u1 = u + row1;

    float2 r[RPT];
#pragma unroll
    for (int j = 0; j < RPT; ++j) {
        const int n = t + NT * j;
        r[j] = make_float2(u0[n], u1[n]);
    }

    fwd_g01(r, t, tw);
    fwd_mid(r, ldsx, ldsy, t, w, l, tw);

    // pointwise multiply in thread-linear W3 order (matches kfft) + 1/N
    {
        const float4* kf4 = (const float4*)(Kf + (size_t)h * FFT_N);
        const float invN = 1.0f / (float)FFT_N;
#pragma unroll
        for (int m = 0; m < 16; ++m) {
            const float4 q = kf4[16 * t + m];
            const float2 z0 = r[2 * m], z1 = r[2 * m + 1];
            r[2 * m]     = make_float2((z0.x * q.x - z0.y * q.y) * invN,
                                       (z0.x * q.y + z0.y * q.x) * invN);
            r[2 * m + 1] = make_float2((z1.x * q.z - z1.y * q.w) * invN,
                                       (z1.x * q.w + z1.y * q.z) * invN);
        }
    }

    inv_mid(r, ldsx, ldsy, t, w, l, tw);
    inv_g01(r, t, tw);

    float* o0 = out + row0;
    float* o1 = out + row1;
#pragma unroll
    for (int j = 0; j < RPT; ++j) {
        const int n = t + NT * j;
        o0[n] = ftanh(r[j].x);
        o1[n] = ftanh(r[j].y);
    }
}

extern "C" void kernel_launch(void* const* d_in, const int* in_sizes, int n_in,
                              void* d_out, int out_size, void* d_ws, size_t ws_size,
                              hipStream_t stream) {
    const float* u = (const float*)d_in[0];   // (B,H,L) f32
    const float* k = (const float*)d_in[1];   // (H,L)   f32
    const float* D = (const float*)d_in[2];   // (H,H)   f32
    float* out = (float*)d_out;

    float2* tw = (float2*)d_ws;               // 16384 float2 = 128 KiB
    float2* Kf = tw + FFT_N;                  // 256*16384 float2 = 32 MiB

    twiddle_init<<<FFT_N / 256, 256, 0, stream>>>(tw);
    kfft_kernel<<<H_DIM, NT, 0, stream>>>(k, D, tw, Kf);
    conv_kernel<<<(B_DIM / 2) * H_DIM, NT, 0, stream>>>(u, tw, Kf, out);
}